// Round 4
// baseline (529.456 us; speedup 1.0000x reference)
//
#include <hip/hip_runtime.h>
#include <hip/hip_bf16.h>

// Problem constants
#define NBATCH 32
#define NTIME  2048
#define NOBJ   18
#define KIN    1500
#define NH     512
#define NTOT   1536   // 2H + DOUT
#define NM     65536  // NBATCH*NTIME

typedef __attribute__((ext_vector_type(4))) float f32x4;
typedef __attribute__((ext_vector_type(8))) short s16x8;
typedef __attribute__((ext_vector_type(4))) short s16x4;

static __device__ __forceinline__ short f2bf(float f) {
  union { float f; unsigned u; } v; v.f = f;
  unsigned r = v.u + 0x7fffu + ((v.u >> 16) & 1u);
  return (short)(r >> 16);
}

static __device__ __forceinline__ void gload_lds16(const short* g, short* l) {
  __builtin_amdgcn_global_load_lds(
      (const __attribute__((address_space(1))) unsigned int*)(g),
      (__attribute__((address_space(3))) unsigned int*)(l), 16, 0, 0);
}

#define FENCE() asm volatile("" ::: "memory")
#define BAR()   do { FENCE(); __builtin_amdgcn_s_barrier(); FENCE(); } while (0)

// Transpose+convert+pad src[K][Nsrc] f32 -> bf16 chunks [cb][kt][row256][kc64],
// with the LDS XOR swizzle baked into the global layout (kc ^ ((row&7)<<3)).
__global__ void k_prep(const float* __restrict__ src, short* __restrict__ dst,
                       int K, int Nsrc, int nkt, int total) {
  int i = blockIdx.x * 256 + threadIdx.x;
  if (i >= total) return;
  int chunk = i >> 14, off = i & 16383;
  int row = off >> 6, kcp = off & 63;
  int kc = kcp ^ ((row & 7) << 3);
  int cb = chunk / nkt, kt = chunk - cb * nkt;
  int n = cb * 256 + row, k = kt * 64 + kc;
  dst[i] = (k < K) ? f2bf(src[(size_t)k * Nsrc + n]) : (short)0;
}

// trip [NM][KIN] f32 -> Ac chunks [rb(256 rows)][kt(24)][row256][kc64] bf16,
// XOR-swizzled, K zero-padded to 1536. One thread = one 8-elem granule; the
// swizzle permutes whole 8-elem granules (XOR hits bits 3..5 only), so the
// source read is one contiguous 32 B (two aligned float4).
__global__ void k_prepA(const float* __restrict__ src, short* __restrict__ dst) {
  int i = blockIdx.x * 256 + threadIdx.x;   // granule idx; 12,582,912 total
  int chunk = i >> 11;                      // 2048 granules per chunk
  int off = i & 2047;
  int row = off >> 3, g = off & 7;
  int rb = chunk / 24, kt = chunk - rb * 24;
  int gs = g ^ (row & 7);
  int m = rb * 256 + row;
  int k0 = kt * 64 + gs * 8;
  const float* p = src + (size_t)m * KIN + k0;
  s16x8 o;
  if (k0 + 8 <= KIN) {
    float4 a = *(const float4*)p, b = *(const float4*)(p + 4);
    o[0] = f2bf(a.x); o[1] = f2bf(a.y); o[2] = f2bf(a.z); o[3] = f2bf(a.w);
    o[4] = f2bf(b.x); o[5] = f2bf(b.y); o[6] = f2bf(b.z); o[7] = f2bf(b.w);
  } else {
#pragma unroll
    for (int j = 0; j < 8; ++j) o[j] = (k0 + j < KIN) ? f2bf(p[j]) : (short)0;
  }
  *(s16x8*)&dst[(size_t)chunk * 16384 + off * 8] = o;
}

__global__ void k_zero(float* __restrict__ p, int n) {
  int i = blockIdx.x * 256 + threadIdx.x;
  if (i < n) p[i] = 0.f;
}

// GEMM1: h = relu(trip_bf16 @ w1a + b1a). PURE-DMA: both operands
// global_load_lds'd from pre-swizzled chunks (A via k_prepA). 256x256 tile,
// BK=64, ONE barrier + one drain per K-tile, next tile prefetched at p0.
__launch_bounds__(512, 2)
__global__ void k_gemm1(const short* __restrict__ Ac, const short* __restrict__ Bc,
                        const float* __restrict__ bias, short* __restrict__ Hc) {
  __shared__ short lA[2][256 * 64];
  __shared__ short lB[2][256 * 64];
  const int g = blockIdx.x;
  const int lid = (g & 7) * 64 + (g >> 3);   // 512 blocks, bijective XCD swizzle
  const int rb = lid >> 1, cb = lid & 1;
  const int m0 = rb * 256, n0 = cb * 256;
  const int tid = threadIdx.x;
  const int lane = tid & 63, w = tid >> 6;
  const int wr = w >> 2, wc = w & 3;
  const int rlane = lane & 15, ksel = (lane >> 4) * 8;
  const int swz = (rlane & 7) << 3;
  const int kx0 = ksel ^ swz, kx1 = (32 | ksel) ^ swz;
  const short* achunk = Ac + (size_t)(rb * 24) * 16384;
  const short* bchunk = Bc + (size_t)(cb * 24) * 16384;

  f32x4 acc[8][4] = {};
  s16x8 af[4][2], bf0[2][2], bf1[2][2];

  auto issueA_full = [&](int nb, int kt) {
    const short* src = achunk + (size_t)kt * 16384 + tid * 8;
#pragma unroll
    for (int j = 0; j < 4; ++j)
      gload_lds16(src + j * 4096, &lA[nb][tid * 8 + j * 4096]);
  };
  auto issueB_full = [&](int nb, int kt) {
    const short* src = bchunk + (size_t)kt * 16384 + tid * 8;
#pragma unroll
    for (int j = 0; j < 4; ++j)
      gload_lds16(src + j * 4096, &lB[nb][tid * 8 + j * 4096]);
  };
  auto readA = [&](int cu, int rh) {
#pragma unroll
    for (int mm = 0; mm < 4; ++mm) {
      int ro = (rh * 128 + wr * 64 + mm * 16 + rlane) * 64;
      af[mm][0] = *(const s16x8*)&lA[cu][ro + kx0];
      af[mm][1] = *(const s16x8*)&lA[cu][ro + kx1];
    }
  };
  auto readB = [&](int cu, int ch, s16x8 (&dst)[2][2]) {
#pragma unroll
    for (int qn = 0; qn < 2; ++qn) {
      int ro = (ch * 128 + wc * 32 + qn * 16 + rlane) * 64;
      dst[qn][0] = *(const s16x8*)&lB[cu][ro + kx0];
      dst[qn][1] = *(const s16x8*)&lB[cu][ro + kx1];
    }
  };
  auto mfma_quad = [&](int rh, int ch, s16x8 (&bfr)[2][2]) {
    __builtin_amdgcn_s_setprio(1);
#pragma unroll
    for (int j = 0; j < 2; ++j)
#pragma unroll
      for (int mm = 0; mm < 4; ++mm)
#pragma unroll
        for (int qn = 0; qn < 2; ++qn)
          acc[rh * 4 + mm][ch * 2 + qn] = __builtin_amdgcn_mfma_f32_16x16x32_bf16(
              af[mm][j], bfr[qn][j], acc[rh * 4 + mm][ch * 2 + qn], 0, 0, 0);
    __builtin_amdgcn_s_setprio(0);
  };

  issueA_full(0, 0);
  issueB_full(0, 0);
  asm volatile("s_waitcnt vmcnt(0)" ::: "memory");
  BAR();

#pragma unroll 1
  for (int kt = 0; kt < 24; ++kt) {
    const int cu = kt & 1, nb = cu ^ 1;
    readA(cu, 0); readB(cu, 0, bf0);
    if (kt < 23) { issueA_full(nb, kt + 1); issueB_full(nb, kt + 1); }
    mfma_quad(0, 0, bf0);
    readB(cu, 1, bf1);
    mfma_quad(0, 1, bf1);
    readA(cu, 1);
    mfma_quad(1, 1, bf1);
    mfma_quad(1, 0, bf0);
    if (kt < 23) {
      asm volatile("s_waitcnt vmcnt(0)" ::: "memory");
      BAR();
    }
  }

  // epilogue: bias + relu, store as chunked-swizzled bf16 for GEMM2's A DMA
#pragma unroll
  for (int n = 0; n < 4; ++n) {
    int c = n0 + (n >> 1) * 128 + wc * 32 + (n & 1) * 16 + rlane;
    float bv = bias[c];
#pragma unroll
    for (int m = 0; m < 8; ++m) {
      int rbase = m0 + (m >> 2) * 128 + wr * 64 + (m & 3) * 16 + ((lane >> 4) << 2);
#pragma unroll
      for (int q = 0; q < 4; ++q) {
        int r = rbase + q;
        float v = acc[m][n][q] + bv;
        v = v > 0.f ? v : 0.f;
        Hc[(size_t)(((r >> 8) * 8 + (c >> 6)) * 16384) + (r & 255) * 64 +
           ((c & 63) ^ ((r & 7) << 3))] = f2bf(v);
      }
    }
  }
}

// GEMM2: new_t = relu(h @ w1b + b1b). Both operands full-tile DMA'd from
// pre-swizzled chunks. Same single-barrier structure as GEMM1.
__launch_bounds__(512, 2)
__global__ void k_gemm2(const short* __restrict__ Ac, const short* __restrict__ Bc,
                        const float* __restrict__ bias, const int* __restrict__ index,
                        const int* __restrict__ rel_lens,
                        float* __restrict__ contrib, float* __restrict__ out) {
  __shared__ short lA[2][256 * 64];
  __shared__ short lB[2][256 * 64];
  const int g = blockIdx.x;
  const int lid = (g & 7) * 192 + (g >> 3);   // 1536 blocks, bijective
  const int rb = lid / 6, cb = lid - rb * 6;
  const int m0 = rb * 256;
  const int tid = threadIdx.x;
  const int lane = tid & 63, w = tid >> 6;
  const int wr = w >> 2, wc = w & 3;
  const int rlane = lane & 15, ksel = (lane >> 4) * 8;
  const int swz = (rlane & 7) << 3;
  const int kx0 = ksel ^ swz, kx1 = (32 | ksel) ^ swz;
  const short* achunk = Ac + (size_t)(rb * 8) * 16384;
  const short* bchunk = Bc + (size_t)(cb * 8) * 16384;

  f32x4 acc[8][4] = {};
  s16x8 af[4][2], bf0[2][2], bf1[2][2];

  auto issueA_full = [&](int nb, int kt) {
    const short* src = achunk + (size_t)kt * 16384 + tid * 8;
#pragma unroll
    for (int j = 0; j < 4; ++j)
      gload_lds16(src + j * 4096, &lA[nb][tid * 8 + j * 4096]);
  };
  auto issueB_full = [&](int nb, int kt) {
    const short* src = bchunk + (size_t)kt * 16384 + tid * 8;
#pragma unroll
    for (int j = 0; j < 4; ++j)
      gload_lds16(src + j * 4096, &lB[nb][tid * 8 + j * 4096]);
  };
  auto readA = [&](int cu, int rh) {
#pragma unroll
    for (int mm = 0; mm < 4; ++mm) {
      int ro = (rh * 128 + wr * 64 + mm * 16 + rlane) * 64;
      af[mm][0] = *(const s16x8*)&lA[cu][ro + kx0];
      af[mm][1] = *(const s16x8*)&lA[cu][ro + kx1];
    }
  };
  auto readB = [&](int cu, int ch, s16x8 (&dst)[2][2]) {
#pragma unroll
    for (int qn = 0; qn < 2; ++qn) {
      int ro = (ch * 128 + wc * 32 + qn * 16 + rlane) * 64;
      dst[qn][0] = *(const s16x8*)&lB[cu][ro + kx0];
      dst[qn][1] = *(const s16x8*)&lB[cu][ro + kx1];
    }
  };
  auto mfma_quad = [&](int rh, int ch, s16x8 (&bfr)[2][2]) {
    __builtin_amdgcn_s_setprio(1);
#pragma unroll
    for (int j = 0; j < 2; ++j)
#pragma unroll
      for (int mm = 0; mm < 4; ++mm)
#pragma unroll
        for (int qn = 0; qn < 2; ++qn)
          acc[rh * 4 + mm][ch * 2 + qn] = __builtin_amdgcn_mfma_f32_16x16x32_bf16(
              af[mm][j], bfr[qn][j], acc[rh * 4 + mm][ch * 2 + qn], 0, 0, 0);
    __builtin_amdgcn_s_setprio(0);
  };

  issueA_full(0, 0);
  issueB_full(0, 0);
  asm volatile("s_waitcnt vmcnt(0)" ::: "memory");
  BAR();

#pragma unroll 1
  for (int kt = 0; kt < 8; ++kt) {
    const int cu = kt & 1, nb = cu ^ 1;
    readA(cu, 0); readB(cu, 0, bf0);
    if (kt < 7) { issueA_full(nb, kt + 1); issueB_full(nb, kt + 1); }
    mfma_quad(0, 0, bf0);
    readB(cu, 1, bf1);
    mfma_quad(0, 1, bf1);
    readA(cu, 1);
    mfma_quad(1, 1, bf1);
    mfma_quad(1, 0, bf0);
    if (kt < 7) {
      asm volatile("s_waitcnt vmcnt(0)" ::: "memory");
      BAR();
    }
  }

  const int region = cb >> 1;  // 0: s, 1: p, 2: o
  float bv[4]; int cg[4];
#pragma unroll
  for (int n = 0; n < 4; ++n) {
    cg[n] = cb * 256 + (n >> 1) * 128 + wc * 32 + (n & 1) * 16 + rlane;
    bv[n] = bias[cg[n]];
  }

  if (region == 1) {
    float* po = out + (size_t)NBATCH * NOBJ * NH;  // p_vecs region of d_out
#pragma unroll
    for (int m = 0; m < 8; ++m) {
      int rbase = m0 + (m >> 2) * 128 + wr * 64 + (m & 3) * 16 + ((lane >> 4) << 2);
#pragma unroll
      for (int q = 0; q < 4; ++q) {
#pragma unroll
        for (int n = 0; n < 4; ++n) {
          float v = acc[m][n][q] + bv[n];
          v = v > 0.f ? v : 0.f;
          po[(size_t)(rbase + q) * NH + (cg[n] & 511)] = v;
        }
      }
    }
  } else {
    const int sel = region >> 1;          // 0 for s, 1 for o
    const int b = m0 >> 11;               // tile is within one batch
    const int rel = rel_lens[b];
#pragma unroll
    for (int m = 0; m < 8; ++m) {
      int rbase = m0 + (m >> 2) * 128 + wr * 64 + (m & 3) * 16 + ((lane >> 4) << 2);
#pragma unroll
      for (int q = 0; q < 4; ++q) {
        int r = rbase + q;
        if ((r & 2047) < rel) {
          int idx = index[2 * r + sel];
          float* dst = contrib + ((b * NOBJ + idx) << 9);
#pragma unroll
          for (int n = 0; n < 4; ++n) {
            float v = acc[m][n][q] + bv[n];
            v = v > 0.f ? v : 0.f;
            atomicAdd(dst + (cg[n] & 511), v);
          }
        }
      }
    }
  }
}

// pooled[b] = cumsum_b(contrib)
__global__ void k_cumsum(const float* __restrict__ contrib, float* __restrict__ pooled) {
  int i = blockIdx.x * 256 + threadIdx.x;
  if (i >= NOBJ * NH) return;
  float a = 0.f;
#pragma unroll
  for (int b = 0; b < NBATCH; ++b) {
    a += contrib[b * (NOBJ * NH) + i];
    pooled[b * (NOBJ * NH) + i] = a;
  }
}

// new_obj = relu(relu(pooled @ w2a + b2a) @ w2b + b2b), one block per (b,o) row
__global__ void k_mlp2(const float* __restrict__ pooled,
                       const float* __restrict__ w2a, const float* __restrict__ b2a,
                       const float* __restrict__ w2b, const float* __restrict__ b2b,
                       float* __restrict__ out) {
  __shared__ float pr[NH];
  __shared__ float hr[NH];
  int row = blockIdx.x;
  int tid = threadIdx.x;
  pr[tid]       = pooled[(size_t)row * NH + tid];
  pr[tid + 256] = pooled[(size_t)row * NH + tid + 256];
  __syncthreads();
  float s0 = 0.f, s1 = 0.f;
  for (int k = 0; k < NH; ++k) {
    float p = pr[k];
    s0 += p * w2a[k * NH + tid];
    s1 += p * w2a[k * NH + tid + 256];
  }
  s0 += b2a[tid]; s1 += b2a[tid + 256];
  hr[tid]       = s0 > 0.f ? s0 : 0.f;
  hr[tid + 256] = s1 > 0.f ? s1 : 0.f;
  __syncthreads();
  s0 = 0.f; s1 = 0.f;
  for (int k = 0; k < NH; ++k) {
    float h = hr[k];
    s0 += h * w2b[k * NH + tid];
    s1 += h * w2b[k * NH + tid + 256];
  }
  s0 += b2b[tid]; s1 += b2b[tid + 256];
  out[(size_t)row * NH + tid]       = s0 > 0.f ? s0 : 0.f;
  out[(size_t)row * NH + tid + 256] = s1 > 0.f ? s1 : 0.f;
}

extern "C" void kernel_launch(void* const* d_in, const int* in_sizes, int n_in,
                              void* d_out, int out_size, void* d_ws, size_t ws_size,
                              hipStream_t stream) {
  const float* trip     = (const float*)d_in[0];
  const int*   index    = (const int*)d_in[1];
  const int*   rel_lens = (const int*)d_in[2];
  const float* w1a      = (const float*)d_in[3];
  const float* b1a      = (const float*)d_in[4];
  const float* w1b      = (const float*)d_in[5];
  const float* b1b      = (const float*)d_in[6];
  const float* w2a      = (const float*)d_in[7];
  const float* b2a      = (const float*)d_in[8];
  const float* w2b      = (const float*)d_in[9];
  const float* b2b      = (const float*)d_in[10];
  float* out = (float*)d_out;

  char* ws = (char*)d_ws;
  short* wt1a    = (short*)(ws);                          // 512*1536 bf16   (1.50 MB)
  short* wt1b    = (short*)(ws + 1572864);                // 1536*512 bf16   (1.50 MB)
  short* hbuf    = (short*)(ws + 3145728);                // 65536*512 bf16  (64 MB), chunked
  float* contrib = (float*)(ws + 70254592);               // 32*18*512 f32
  float* pooled  = contrib + NBATCH * NOBJ * NH;
  short* abuf    = (short*)(ws + 75497472);               // 65536*1536 bf16 (201 MB), chunked

  k_zero<<<1152, 256, 0, stream>>>(contrib, NBATCH * NOBJ * NH);
  k_prep<<<3072, 256, 0, stream>>>(w1a, wt1a, KIN, NH, 24, NH * 1536);
  k_prep<<<3072, 256, 0, stream>>>(w1b, wt1b, NH, NTOT, 8, NTOT * NH);
  k_prepA<<<49152, 256, 0, stream>>>(trip, abuf);
  k_gemm1<<<512, 512, 0, stream>>>(abuf, wt1a, b1a, hbuf);
  k_gemm2<<<1536, 512, 0, stream>>>(hbuf, wt1b, b1b, index, rel_lens, contrib, out);
  k_cumsum<<<36, 256, 0, stream>>>(contrib, pooled);
  k_mlp2<<<576, 256, 0, stream>>>(pooled, w2a, b2a, w2b, b2b, out);
}

// Round 6
// 475.661 us; speedup vs baseline: 1.1131x; 1.1131x over previous
//
#include <hip/hip_runtime.h>
#include <hip/hip_bf16.h>

// Problem constants
#define NBATCH 32
#define NTIME  2048
#define NOBJ   18
#define KIN    1500
#define NH     512
#define NTOT   1536   // 2H + DOUT
#define NM     65536  // NBATCH*NTIME

typedef __attribute__((ext_vector_type(4))) float f32x4;
typedef __attribute__((ext_vector_type(8))) short s16x8;
typedef __attribute__((ext_vector_type(4))) short s16x4;

static __device__ __forceinline__ short f2bf(float f) {
  union { float f; unsigned u; } v; v.f = f;
  unsigned r = v.u + 0x7fffu + ((v.u >> 16) & 1u);
  return (short)(r >> 16);
}

static __device__ __forceinline__ void gload_lds16(const short* g, short* l) {
  __builtin_amdgcn_global_load_lds(
      (const __attribute__((address_space(1))) unsigned int*)(g),
      (__attribute__((address_space(3))) unsigned int*)(l), 16, 0, 0);
}

// Transpose+convert+pad src[K][Nsrc] f32 -> bf16 chunks [cb][kt][row256][kc64],
// with the LDS XOR swizzle baked into the global layout (kc ^ ((row&7)<<3)).
__global__ void k_prep(const float* __restrict__ src, short* __restrict__ dst,
                       int K, int Nsrc, int nkt, int total) {
  int i = blockIdx.x * 256 + threadIdx.x;
  if (i >= total) return;
  int chunk = i >> 14, off = i & 16383;
  int row = off >> 6, kcp = off & 63;
  int kc = kcp ^ ((row & 7) << 3);
  int cb = chunk / nkt, kt = chunk - cb * nkt;
  int n = cb * 256 + row, k = kt * 64 + kc;
  dst[i] = (k < K) ? f2bf(src[(size_t)k * Nsrc + n]) : (short)0;
}

__global__ void k_zero(float* __restrict__ p, int n) {
  int i = blockIdx.x * 256 + threadIdx.x;
  if (i < n) p[i] = 0.f;
}

// GEMM1: h = relu(trip @ w1a + b1a). A f32 [NM][1500] reg-staged (issue-early,
// write-late); B bf16 pre-swizzled chunks via global_load_lds. Tile 64x256,
// BK=64, double-buffered, ONE barrier per K-step. 8 waves (2x4), wave 32x64.
// Output written as chunked-swizzled layout: chunk id (r>>7)*8 + (c>>6),
// chunk = 8192 shorts (128 rows x 64 cols), densely filling hbuf.
// (round-0 measured-best variant: 227 us, VGPR 52, 2 blocks/CU)
__launch_bounds__(512, 2)
__global__ void k_gemm1(const float* __restrict__ A, const short* __restrict__ Bc,
                        const float* __restrict__ bias, short* __restrict__ Hc) {
  __shared__ short lA[2][64 * 64];    // 16 KB
  __shared__ short lB[2][256 * 64];   // 64 KB
  const int g = blockIdx.x;
  const int lid = (g & 7) * 256 + (g >> 3);   // 2048 blocks, bijective
  const int rb = lid >> 1, cb = lid & 1;
  const int m0 = rb * 64, n0 = cb * 256;
  const int tid = threadIdx.x;
  const int lane = tid & 63, w = tid >> 6;
  const int wr = w >> 2, wc = w & 3;
  const int rlane = lane & 15, ksel = (lane >> 4) * 8;
  const int arow = tid >> 4;          // 0..31
  const int akq  = (tid & 15) * 4;    // 0..60
  const short* bchunk = Bc + (size_t)(cb * 24) * 16384;

  f32x4 acc[2][4] = {};
  float4 av[2];

  auto issue_stage = [&](int nb, int kt) {
    // A loads first (oldest in vmcnt queue -> cvt can start before DMA drains)
    const int kbase = kt * 64;
    const bool fullq = (kt < 23) | (akq <= 24);  // K=1500, quad-aligned tail
#pragma unroll
    for (int ri = 0; ri < 2; ++ri) {
      const float* p = A + (size_t)(m0 + arow + ri * 32) * KIN + kbase + akq;
      av[ri] = fullq ? *(const float4*)p : make_float4(0.f, 0.f, 0.f, 0.f);
    }
    const short* src = bchunk + (size_t)kt * 16384 + tid * 8;
#pragma unroll
    for (int i = 0; i < 4; ++i)
      gload_lds16(src + i * 4096, &lB[nb][tid * 8 + i * 4096]);
  };
  auto write_stage = [&](int nb) {
#pragma unroll
    for (int ri = 0; ri < 2; ++ri) {
      int row = arow + ri * 32;
      s16x4 h4;
      h4[0] = f2bf(av[ri].x); h4[1] = f2bf(av[ri].y);
      h4[2] = f2bf(av[ri].z); h4[3] = f2bf(av[ri].w);
      *(s16x4*)&lA[nb][row * 64 + (akq ^ ((row & 7) << 3))] = h4;
    }
  };
  auto compute = [&](int cu) {
#pragma unroll
    for (int j = 0; j < 2; ++j) {
      int k0 = j * 32 + ksel;
      s16x8 af[2], bfr[4];
#pragma unroll
      for (int m = 0; m < 2; ++m) {
        int row = wr * 32 + m * 16 + rlane;
        af[m] = *(const s16x8*)&lA[cu][row * 64 + (k0 ^ ((row & 7) << 3))];
      }
#pragma unroll
      for (int n = 0; n < 4; ++n) {
        int row = wc * 64 + n * 16 + rlane;
        bfr[n] = *(const s16x8*)&lB[cu][row * 64 + (k0 ^ ((row & 7) << 3))];
      }
#pragma unroll
      for (int m = 0; m < 2; ++m)
#pragma unroll
        for (int n = 0; n < 4; ++n)
          acc[m][n] = __builtin_amdgcn_mfma_f32_16x16x32_bf16(af[m], bfr[n], acc[m][n], 0, 0, 0);
    }
  };

  issue_stage(0, 0);
  write_stage(0);
  asm volatile("s_waitcnt vmcnt(0)" ::: "memory");
  __syncthreads();
  for (int kt = 0; kt < 24; ++kt) {
    const int cu = kt & 1;
    if (kt < 23) issue_stage(cu ^ 1, kt + 1);
    compute(cu);
    if (kt < 23) {
      write_stage(cu ^ 1);
      asm volatile("s_waitcnt vmcnt(0)" ::: "memory");
      __syncthreads();
    }
  }

  // epilogue: bias + relu, store to chunked-swizzled layout for GEMM2's A
#pragma unroll
  for (int n = 0; n < 4; ++n) {
    int c = n0 + wc * 64 + n * 16 + rlane;
    float bv = bias[c];
#pragma unroll
    for (int m = 0; m < 2; ++m) {
      int rbase = m0 + wr * 32 + m * 16 + ((lane >> 4) << 2);
#pragma unroll
      for (int q = 0; q < 4; ++q) {
        int r = rbase + q;
        float v = acc[m][n][q] + bv;
        v = v > 0.f ? v : 0.f;
        Hc[(size_t)(((r >> 7) * 8 + (c >> 6)) * 8192) + (r & 127) * 64 +
           ((c & 63) ^ ((r & 7) << 3))] = f2bf(v);
      }
    }
  }
}

// GEMM2: new_t = relu(h @ w1b + b1b), both operands DMA from pre-swizzled
// chunks; round-0 core + DEAD-TILE EARLY-EXIT: s/o-region tiles whose whole
// 64-row range is masked out (local row start >= rel_lens[b]) contribute
// nothing (the scatter guard would reject every row) -> return immediately.
// Removes ~32% of gemm2's work in expectation (rel ~ U[0,2048)).
// achunk stride: (m0>>7) 128-row blocks of 8 chunks x 8192 shorts (matches
// gemm1's writer exactly; 16384 here was the round-5 correctness bug).
__launch_bounds__(512, 2)
__global__ void k_gemm2(const short* __restrict__ Ac, const short* __restrict__ Bc,
                        const float* __restrict__ bias, const int* __restrict__ index,
                        const int* __restrict__ rel_lens,
                        float* __restrict__ contrib, float* __restrict__ out) {
  __shared__ short lA[2][64 * 64];
  __shared__ short lB[2][256 * 64];
  const int g = blockIdx.x;
  const int lid = (g & 7) * 768 + (g >> 3);   // 6144 blocks, bijective
  const int rb = lid / 6, cb = lid - rb * 6;
  const int m0 = rb * 64, n0 = cb * 256;
  const int region = n0 >> 9;  // 0: s, 1: p, 2: o
  const int b = m0 >> 11;      // tile is within one batch
  const int rel = rel_lens[b];
  if (region != 1 && (m0 & 2047) >= rel) return;  // dead s/o tile: exact skip

  const int tid = threadIdx.x;
  const int lane = tid & 63, w = tid >> 6;
  const int wr = w >> 2, wc = w & 3;
  const int rlane = lane & 15, ksel = (lane >> 4) * 8;
  const short* achunk = Ac + (size_t)((m0 >> 7) * 8) * 8192 + (m0 & 127) * 64;
  const short* bchunk = Bc + (size_t)(cb * 8) * 16384;

  f32x4 acc[2][4] = {};

  auto issue_stage = [&](int nb, int kt) {
    gload_lds16(achunk + (size_t)kt * 8192 + tid * 8, &lA[nb][tid * 8]);
    const short* src = bchunk + (size_t)kt * 16384 + tid * 8;
#pragma unroll
    for (int i = 0; i < 4; ++i)
      gload_lds16(src + i * 4096, &lB[nb][tid * 8 + i * 4096]);
  };
  auto compute = [&](int cu) {
#pragma unroll
    for (int j = 0; j < 2; ++j) {
      int k0 = j * 32 + ksel;
      s16x8 af[2], bfr[4];
#pragma unroll
      for (int m = 0; m < 2; ++m) {
        int row = wr * 32 + m * 16 + rlane;
        af[m] = *(const s16x8*)&lA[cu][row * 64 + (k0 ^ ((row & 7) << 3))];
      }
#pragma unroll
      for (int n = 0; n < 4; ++n) {
        int row = wc * 64 + n * 16 + rlane;
        bfr[n] = *(const s16x8*)&lB[cu][row * 64 + (k0 ^ ((row & 7) << 3))];
      }
#pragma unroll
      for (int m = 0; m < 2; ++m)
#pragma unroll
        for (int n = 0; n < 4; ++n)
          acc[m][n] = __builtin_amdgcn_mfma_f32_16x16x32_bf16(af[m], bfr[n], acc[m][n], 0, 0, 0);
    }
  };

  issue_stage(0, 0);
  asm volatile("s_waitcnt vmcnt(0)" ::: "memory");
  __syncthreads();
  for (int kt = 0; kt < 8; ++kt) {
    const int cu = kt & 1;
    if (kt < 7) issue_stage(cu ^ 1, kt + 1);
    compute(cu);
    if (kt < 7) {
      asm volatile("s_waitcnt vmcnt(0)" ::: "memory");
      __syncthreads();
    }
  }

  float bv[4]; int cg[4];
#pragma unroll
  for (int n = 0; n < 4; ++n) { cg[n] = n0 + wc * 64 + n * 16 + rlane; bv[n] = bias[cg[n]]; }

  if (region == 1) {
    float* po = out + (size_t)NBATCH * NOBJ * NH;  // p_vecs region of d_out
#pragma unroll
    for (int m = 0; m < 2; ++m) {
      int rbase = m0 + wr * 32 + m * 16 + ((lane >> 4) << 2);
#pragma unroll
      for (int q = 0; q < 4; ++q) {
#pragma unroll
        for (int n = 0; n < 4; ++n) {
          float v = acc[m][n][q] + bv[n];
          v = v > 0.f ? v : 0.f;
          po[(size_t)(rbase + q) * NH + (cg[n] & 511)] = v;
        }
      }
    }
  } else {
    const int sel = region >> 1;          // 0 for s, 1 for o
#pragma unroll
    for (int m = 0; m < 2; ++m) {
      int rbase = m0 + wr * 32 + m * 16 + ((lane >> 4) << 2);
#pragma unroll
      for (int q = 0; q < 4; ++q) {
        int r = rbase + q;
        if ((r & 2047) < rel) {
          int idx = index[2 * r + sel];
          float* dst = contrib + ((b * NOBJ + idx) << 9);
#pragma unroll
          for (int n = 0; n < 4; ++n) {
            float v = acc[m][n][q] + bv[n];
            v = v > 0.f ? v : 0.f;
            atomicAdd(dst + (cg[n] & 511), v);
          }
        }
      }
    }
  }
}

// pooled[b] = cumsum_b(contrib)
__global__ void k_cumsum(const float* __restrict__ contrib, float* __restrict__ pooled) {
  int i = blockIdx.x * 256 + threadIdx.x;
  if (i >= NOBJ * NH) return;
  float a = 0.f;
#pragma unroll
  for (int b = 0; b < NBATCH; ++b) {
    a += contrib[b * (NOBJ * NH) + i];
    pooled[b * (NOBJ * NH) + i] = a;
  }
}

// new_obj = relu(relu(pooled @ w2a + b2a) @ w2b + b2b), one block per (b,o)
// row. 4 independent FMA chains per thread (k-unroll 2 x 2 outputs) to break
// the 512-long dependent-accumulation latency chain.
__global__ void k_mlp2(const float* __restrict__ pooled,
                       const float* __restrict__ w2a, const float* __restrict__ b2a,
                       const float* __restrict__ w2b, const float* __restrict__ b2b,
                       float* __restrict__ out) {
  __shared__ float pr[NH];
  __shared__ float hr[NH];
  int row = blockIdx.x;
  int tid = threadIdx.x;
  pr[tid]       = pooled[(size_t)row * NH + tid];
  pr[tid + 256] = pooled[(size_t)row * NH + tid + 256];
  __syncthreads();
  {
    float a0 = 0.f, a1 = 0.f, b0 = 0.f, b1 = 0.f;
    for (int k = 0; k < NH; k += 2) {
      float p0 = pr[k], p1 = pr[k + 1];
      a0 += p0 * w2a[(size_t)k * NH + tid];
      b0 += p0 * w2a[(size_t)k * NH + tid + 256];
      a1 += p1 * w2a[(size_t)(k + 1) * NH + tid];
      b1 += p1 * w2a[(size_t)(k + 1) * NH + tid + 256];
    }
    float s0 = a0 + a1 + b2a[tid], s1 = b0 + b1 + b2a[tid + 256];
    hr[tid]       = s0 > 0.f ? s0 : 0.f;
    hr[tid + 256] = s1 > 0.f ? s1 : 0.f;
  }
  __syncthreads();
  {
    float a0 = 0.f, a1 = 0.f, b0 = 0.f, b1 = 0.f;
    for (int k = 0; k < NH; k += 2) {
      float h0 = hr[k], h1 = hr[k + 1];
      a0 += h0 * w2b[(size_t)k * NH + tid];
      b0 += h0 * w2b[(size_t)k * NH + tid + 256];
      a1 += h1 * w2b[(size_t)(k + 1) * NH + tid];
      b1 += h1 * w2b[(size_t)(k + 1) * NH + tid + 256];
    }
    float s0 = a0 + a1 + b2b[tid], s1 = b0 + b1 + b2b[tid + 256];
    out[(size_t)row * NH + tid]       = s0 > 0.f ? s0 : 0.f;
    out[(size_t)row * NH + tid + 256] = s1 > 0.f ? s1 : 0.f;
  }
}

extern "C" void kernel_launch(void* const* d_in, const int* in_sizes, int n_in,
                              void* d_out, int out_size, void* d_ws, size_t ws_size,
                              hipStream_t stream) {
  const float* trip     = (const float*)d_in[0];
  const int*   index    = (const int*)d_in[1];
  const int*   rel_lens = (const int*)d_in[2];
  const float* w1a      = (const float*)d_in[3];
  const float* b1a      = (const float*)d_in[4];
  const float* w1b      = (const float*)d_in[5];
  const float* b1b      = (const float*)d_in[6];
  const float* w2a      = (const float*)d_in[7];
  const float* b2a      = (const float*)d_in[8];
  const float* w2b      = (const float*)d_in[9];
  const float* b2b      = (const float*)d_in[10];
  float* out = (float*)d_out;

  char* ws = (char*)d_ws;
  short* wt1a    = (short*)(ws);                          // 512*1536 bf16  (1.50 MB)
  short* wt1b    = (short*)(ws + 1572864);                // 1536*512 bf16  (1.50 MB)
  short* hbuf    = (short*)(ws + 3145728);                // 65536*512 bf16 (64 MB), chunked
  float* contrib = (float*)(ws + 70254592);               // 32*18*512 f32
  float* pooled  = contrib + NBATCH * NOBJ * NH;

  k_zero<<<1152, 256, 0, stream>>>(contrib, NBATCH * NOBJ * NH);
  k_prep<<<3072, 256, 0, stream>>>(w1a, wt1a, KIN, NH, 24, NH * 1536);
  k_prep<<<3072, 256, 0, stream>>>(w1b, wt1b, NH, NTOT, 8, NTOT * NH);
  k_gemm1<<<2048, 512, 0, stream>>>(trip, wt1a, b1a, hbuf);
  k_gemm2<<<6144, 512, 0, stream>>>(hbuf, wt1b, b1b, index, rel_lens, contrib, out);
  k_cumsum<<<36, 256, 0, stream>>>(contrib, pooled);
  k_mlp2<<<576, 256, 0, stream>>>(pooled, w2a, b2a, w2b, b2b, out);
}